// Round 3
// baseline (1196.634 us; speedup 1.0000x reference)
//
#include <hip/hip_runtime.h>
#include <hip/hip_bf16.h>

// Problem constants
#define BQ   8
#define NLQ  1024
#define NQ   2048
#define DQ   128

typedef __attribute__((ext_vector_type(4))) float f32x4;
typedef __attribute__((ext_vector_type(8))) short bf16x8;

__device__ __forceinline__ unsigned short bfbits(float f) {
  __hip_bfloat16 h = __float2bfloat16(f);
  return __builtin_bit_cast(unsigned short, h);
}
__device__ __forceinline__ float sigm(float x) { return 1.f / (1.f + expf(-x)); }

// packed bf16 pair add (truncating round — threshold slack is huge)
__device__ __forceinline__ unsigned int bfadd2(unsigned int a, unsigned int b) {
  float alo = __builtin_bit_cast(float, a << 16);
  float ahi = __builtin_bit_cast(float, a & 0xffff0000u);
  float blo = __builtin_bit_cast(float, b << 16);
  float bhi = __builtin_bit_cast(float, b & 0xffff0000u);
  float lo = alo + blo, hi = ahi + bhi;
  return (__builtin_bit_cast(unsigned int, hi) & 0xffff0000u) |
         (__builtin_bit_cast(unsigned int, lo) >> 16);
}

// async global->LDS, 16B per lane. LDS dest is wave-uniform base + lane*16.
__device__ __forceinline__ void g2l16(const void* g, void* l) {
  __builtin_amdgcn_global_load_lds(
      (__attribute__((address_space(1))) void*)(uintptr_t)g,
      (__attribute__((address_space(3))) void*)(uint32_t)(uintptr_t)l,
      16, 0, 0);
}

// ---------------------------------------------------------------------------
// msgs GEMM: partial[kh][b] = adj[b][rows][K-half] @ h[K-half][128]
// Block tile 128x128, 4 waves (2x2), wave tile 64x64, BK=64.
// 3-buffer LDS, 2-deep prefetch, counted vmcnt(8). Grid (16, 1, 16):
// blockIdx.z = batch*2 + khalf. Output: bf16 partials msP[kh].
// ---------------------------------------------------------------------------
__global__ __launch_bounds__(256) void gemm_msgs(
    const __hip_bfloat16* __restrict__ adj,   // [B][2048][2048]
    const __hip_bfloat16* __restrict__ hT,    // [B][128][2048]
    __hip_bfloat16* __restrict__ msP) {       // [2][B][2048][128]
  __shared__ __align__(16) __hip_bfloat16 As[3][128 * 64];
  __shared__ __align__(16) __hip_bfloat16 Bs[3][128 * 64];
  const int t = threadIdx.x, lane = t & 63, w = t >> 6;
  const int wr = w >> 1, wc = w & 1;
  const int bm = blockIdx.x;
  const int batch = blockIdx.z >> 1, kh = blockIdx.z & 1;
  const int kbase = kh * 1024;

  const __hip_bfloat16* aB = adj + (size_t)batch * NQ * NQ + (size_t)bm * 128 * NQ + kbase;
  const __hip_bfloat16* bB = hT + (size_t)batch * DQ * NQ + kbase;

  const int srow = (lane >> 3);                        // + w*32 + q*8
  const int swzCol = ((lane & 7) ^ (lane >> 3)) << 3;  // pre-swizzled source col
  const int lr = lane & 15, lh = lane >> 4;
  const int rswz = (lr & 7) << 3;

  f32x4 acc[4][4] = {};

  auto stage = [&](int bi, int tt) {
    const int k = tt * 64;
#pragma unroll
    for (int q = 0; q < 4; ++q)
      g2l16(aB + (size_t)(w * 32 + q * 8 + srow) * NQ + k + swzCol,
            (char*)As[bi] + w * 4096 + q * 1024);
#pragma unroll
    for (int q = 0; q < 4; ++q)
      g2l16(bB + (size_t)(w * 32 + q * 8 + srow) * NQ + k + swzCol,
            (char*)Bs[bi] + w * 4096 + q * 1024);
  };

  stage(0, 0);
  stage(1, 1);
  asm volatile("s_waitcnt vmcnt(8)" ::: "memory");
  __builtin_amdgcn_s_barrier();

  int cur = 0;
  const int nt = 16;  // 1024 / 64
  for (int tt = 0; tt < nt; ++tt) {
    bf16x8 av[2][4], bv[2][4];
#pragma unroll
    for (int kk = 0; kk < 2; ++kk) {
#pragma unroll
      for (int m = 0; m < 4; ++m)
        av[kk][m] = *(const bf16x8*)&As[cur][(wr * 64 + m * 16 + lr) * 64 +
                                            ((kk * 32 + lh * 8) ^ rswz)];
#pragma unroll
      for (int n = 0; n < 4; ++n)
        bv[kk][n] = *(const bf16x8*)&Bs[cur][(wc * 64 + n * 16 + lr) * 64 +
                                             ((kk * 32 + lh * 8) ^ rswz)];
    }
    if (tt + 2 < nt) {
      int bi = cur + 2; if (bi >= 3) bi -= 3;
      stage(bi, tt + 2);
    }
    __builtin_amdgcn_s_setprio(1);
#pragma unroll
    for (int kk = 0; kk < 2; ++kk)
#pragma unroll
      for (int m = 0; m < 4; ++m)
#pragma unroll
        for (int n = 0; n < 4; ++n)
          acc[m][n] = __builtin_amdgcn_mfma_f32_16x16x32_bf16(av[kk][m], bv[kk][n],
                                                              acc[m][n], 0, 0, 0);
    __builtin_amdgcn_s_setprio(0);
    if (tt < nt - 2) {
      asm volatile("s_waitcnt vmcnt(8)" ::: "memory");
      __builtin_amdgcn_s_barrier();
    } else if (tt == nt - 2) {
      asm volatile("s_waitcnt vmcnt(0)" ::: "memory");
      __builtin_amdgcn_s_barrier();
    }
    ++cur; if (cur == 3) cur = 0;
  }

  __hip_bfloat16* out = msP + (size_t)kh * (BQ * NQ * DQ) + (size_t)batch * NQ * DQ;
#pragma unroll
  for (int m = 0; m < 4; ++m) {
    const int row0 = bm * 128 + wr * 64 + m * 16 + lh * 4;
#pragma unroll
    for (int n = 0; n < 4; ++n) {
      const int col = wc * 64 + n * 16 + lr;
#pragma unroll
      for (int r = 0; r < 4; ++r)
        out[(size_t)(row0 + r) * DQ + col] = __float2bfloat16(acc[m][n][r]);
    }
  }
}

// ---------------------------------------------------------------------------
// Small GEMMs over token rows (M=16384): C = [A0 | msgs-sum] @ BT^T
// Block tile 128x128, wave tile 64x64, BK=64, 2-buffer T14 pipeline.
// A-cols >= 128 come from summing the two bf16 msgs partials (reg-staged).
// EPI: 1 = z/r+rh, 2 = ht+GRU update, 3 = in-proj.
// ---------------------------------------------------------------------------
template <int EPI>
__global__ __launch_bounds__(256) void gemm_small(
    const __hip_bfloat16* __restrict__ A0,   // [16384][128]
    const __hip_bfloat16* __restrict__ ms,   // partial pair base or null
    const __hip_bfloat16* __restrict__ BT,   // [Ncols][K]
    int K,
    const float* __restrict__ bias0, const float* __restrict__ bias1,
    float* __restrict__ hF, float* __restrict__ zF,
    __hip_bfloat16* __restrict__ bf0, __hip_bfloat16* __restrict__ bf1) {
  __shared__ __align__(16) __hip_bfloat16 As[2][128 * 64];
  __shared__ __align__(16) __hip_bfloat16 Bs[2][128 * 64];
  const int t = threadIdx.x, lane = t & 63, w = t >> 6;
  const int wr = w >> 1, wc = w & 1;
  const int bm = blockIdx.x, bn = blockIdx.y;

  const int srow = (lane >> 3);
  const int swzCol = ((lane & 7) ^ (lane >> 3)) << 3;
  const int lr = lane & 15, lh = lane >> 4;
  const int rswz = (lr & 7) << 3;
  const size_t msStride = (size_t)BQ * NQ * DQ;

  const int nt = K >> 6;
  f32x4 acc[4][4] = {};
  uint4 p0[4], p1[4];

  auto issueB = [&](int bi, int tt) {
#pragma unroll
    for (int q = 0; q < 4; ++q)
      g2l16(BT + (size_t)(bn * 128 + w * 32 + q * 8 + srow) * K + tt * 64 + swzCol,
            (char*)Bs[bi] + w * 4096 + q * 1024);
  };
  auto issueA = [&](int bi, int tt) -> bool {
    const int k0 = tt * 64;
    if (k0 < 128 || ms == nullptr) {
#pragma unroll
      for (int q = 0; q < 4; ++q)
        g2l16(A0 + (size_t)(bm * 128 + w * 32 + q * 8 + srow) * 128 + k0 + swzCol,
              (char*)As[bi] + w * 4096 + q * 1024);
      return false;
    }
    const size_t base = (size_t)(bm * 128 + w * 32 + srow) * 128 + (k0 - 128) + swzCol;
#pragma unroll
    for (int q = 0; q < 4; ++q) {
      p0[q] = *(const uint4*)(ms + base + (size_t)q * 1024);
      p1[q] = *(const uint4*)(ms + msStride + base + (size_t)q * 1024);
    }
    return true;
  };
  auto finalize = [&](int bi) {
#pragma unroll
    for (int q = 0; q < 4; ++q) {
      uint4 s;
      s.x = bfadd2(p0[q].x, p1[q].x);
      s.y = bfadd2(p0[q].y, p1[q].y);
      s.z = bfadd2(p0[q].z, p1[q].z);
      s.w = bfadd2(p0[q].w, p1[q].w);
      *(uint4*)((char*)As[bi] + w * 4096 + q * 1024 + lane * 16) = s;
    }
  };
  auto compute = [&](int bi) {
    bf16x8 av[2][4], bv[2][4];
#pragma unroll
    for (int kk = 0; kk < 2; ++kk) {
#pragma unroll
      for (int m = 0; m < 4; ++m)
        av[kk][m] = *(const bf16x8*)&As[bi][(wr * 64 + m * 16 + lr) * 64 +
                                           ((kk * 32 + lh * 8) ^ rswz)];
#pragma unroll
      for (int n = 0; n < 4; ++n)
        bv[kk][n] = *(const bf16x8*)&Bs[bi][(wc * 64 + n * 16 + lr) * 64 +
                                            ((kk * 32 + lh * 8) ^ rswz)];
    }
    __builtin_amdgcn_s_setprio(1);
#pragma unroll
    for (int kk = 0; kk < 2; ++kk)
#pragma unroll
      for (int m = 0; m < 4; ++m)
#pragma unroll
        for (int n = 0; n < 4; ++n)
          acc[m][n] = __builtin_amdgcn_mfma_f32_16x16x32_bf16(av[kk][m], bv[kk][n],
                                                              acc[m][n], 0, 0, 0);
    __builtin_amdgcn_s_setprio(0);
  };

  issueA(0, 0);
  issueB(0, 0);
  asm volatile("s_waitcnt vmcnt(0)" ::: "memory");
  __builtin_amdgcn_s_barrier();

  for (int tt = 0; tt < nt; ++tt) {
    const bool hasNext = (tt + 1 < nt);
    bool reg = false;
    if (hasNext) {
      reg = issueA((tt + 1) & 1, tt + 1);
      issueB((tt + 1) & 1, tt + 1);
    }
    compute(tt & 1);
    if (hasNext) {
      if (reg) finalize((tt + 1) & 1);
      asm volatile("s_waitcnt vmcnt(0) lgkmcnt(0)" ::: "memory");
      __builtin_amdgcn_s_barrier();
    }
  }

  // Epilogue. C/D layout: col = lane&15, row = (lane>>4)*4 + reg.
#pragma unroll
  for (int m = 0; m < 4; ++m) {
    const int gRow = bm * 128 + wr * 64 + m * 16 + lh * 4;
#pragma unroll
    for (int n = 0; n < 4; ++n) {
      const int col = bn * 128 + wc * 64 + n * 16 + lr;
      f32x4 v = acc[m][n];
      if constexpr (EPI == 1) {  // z (bn==0) / r -> r*h (bn==1)
        if (col < 128) {
          const float bb = bias0[col];
#pragma unroll
          for (int r = 0; r < 4; ++r)
            zF[(size_t)(gRow + r) * DQ + col] = sigm(v[r] + bb);
        } else {
          const int c = col - 128;
          const float bb = bias1[c];
#pragma unroll
          for (int r = 0; r < 4; ++r) {
            size_t idx = (size_t)(gRow + r) * DQ + c;
            float rr = sigm(v[r] + bb);
            bf0[idx] = __float2bfloat16(rr * hF[idx]);
          }
        }
      } else {  // EPI 2 (ht + GRU) and EPI 3 (in-proj)
        const float bb = bias0[col];
        ushort4 us;
        unsigned short* up = (unsigned short*)&us;
#pragma unroll
        for (int r = 0; r < 4; ++r) {
          size_t idx = (size_t)(gRow + r) * DQ + col;
          float hn;
          if constexpr (EPI == 2) {
            float tv = tanhf(v[r] + bb);
            float zv = zF[idx];
            float hv = hF[idx];
            hn = zv * hv + (1.f - zv) * tv;
          } else {
            hn = v[r] + bb;
          }
          hF[idx] = hn;
          bf0[idx] = __float2bfloat16(hn);
          up[r] = bfbits(hn);
        }
        const int bb_ = gRow >> 11;
        const int nl = gRow & 2047;
        *(ushort4*)((char*)bf1 + ((size_t)bb_ * (DQ * NQ) + (size_t)col * NQ + nl) * 2) = us;
      }
    }
  }
}

// ---------------------------------------------------------------------------
__global__ void cvt_adj(const float4* __restrict__ in, ushort4* __restrict__ out, int n4) {
  int stride = gridDim.x * blockDim.x;
  for (int i = blockIdx.x * blockDim.x + threadIdx.x; i < n4; i += stride) {
    float4 v = in[i];
    ushort4 o;
    o.x = bfbits(v.x); o.y = bfbits(v.y); o.z = bfbits(v.z); o.w = bfbits(v.w);
    out[i] = o;
  }
}

// Pack weights to bf16, transposed to N x K row-major.
__global__ void pack_weights(const float* __restrict__ ugW, const float* __restrict__ rgW,
                             const float* __restrict__ htW, const float* __restrict__ inW,
                             __hip_bfloat16* __restrict__ wzrT, __hip_bfloat16* __restrict__ htT,
                             __hip_bfloat16* __restrict__ inT) {
  int idx = blockIdx.x * 256 + threadIdx.x;
  if (idx < 5 * 256 * 256) {  // wzrT[i][n][k], n<128 -> ug, else rg
    int i = idx >> 16, r = idx & 65535, nn = r >> 8, k = r & 255;
    float v = (nn < 128) ? ugW[(i * 256 + k) * 128 + nn] : rgW[(i * 256 + k) * 128 + nn - 128];
    wzrT[idx] = __float2bfloat16(v);
    return;
  }
  int j = idx - 5 * 256 * 256;
  if (j < 5 * 128 * 256) {  // htT[i][n][k]
    int i = j >> 15, r = j & 32767, nn = r >> 8, k = r & 255;
    htT[j] = __float2bfloat16(htW[(i * 256 + k) * 128 + nn]);
    return;
  }
  int j2 = j - 5 * 128 * 256;
  if (j2 < 5 * 128 * 128) {  // inT[i][n][k]
    int i = j2 >> 14, r = j2 & 16383, nn = r >> 7, k = r & 127;
    inT[j2] = __float2bfloat16(inW[(i * 128 + k) * 128 + nn]);
  }
}

// Build initial x (bf16) = [tok_emb[input_node] | inputtext] ++ tok_emb1[linenode]
__global__ void build_x(const int* __restrict__ node, const int* __restrict__ text,
                        const int* __restrict__ line, const float* __restrict__ te,
                        const float* __restrict__ te1, __hip_bfloat16* __restrict__ xbf) {
  int idx = blockIdx.x * 256 + threadIdx.x;  // B*N*D = 2M exactly
  int d = idx & 127;
  int p = (idx >> 7) & 2047;
  int b = idx >> 18;
  float v;
  if (p < NLQ) {
    if (d < 127) {
      int id = node[b * NLQ + p];
      v = te[(size_t)id * 127 + d];
    } else {
      v = (float)text[b * NLQ + p];
    }
  } else {
    int id = line[b * NLQ + (p - NLQ)];
    v = te1[(size_t)id * 128 + d];
  }
  xbf[idx] = __float2bfloat16(v);
}

__device__ __forceinline__ float waveMax(float v) {
#pragma unroll
  for (int m = 32; m; m >>= 1) v = fmaxf(v, __shfl_xor(v, m, 64));
  return v;
}
__device__ __forceinline__ float waveSum(float v) {
#pragma unroll
  for (int m = 32; m; m >>= 1) v += __shfl_xor(v, m, 64);
  return v;
}

// logits = h[:, :NL] @ res2_W + b; mask; softmax; loss
__global__ __launch_bounds__(256) void final_k(const float* __restrict__ h,
                                               const float* __restrict__ w2,
                                               const float* __restrict__ b2,
                                               const int* __restrict__ node,
                                               const float* __restrict__ res,
                                               float* __restrict__ outLoss,
                                               float* __restrict__ outSm) {
  int b = blockIdx.x, t = threadIdx.x;
  __shared__ float lw[128];
  __shared__ float lg[NLQ];
  __shared__ float red[4];
  __shared__ float bc;
  if (t < 128) lw[t] = w2[t];
  __syncthreads();
  float bias = b2[0];
  for (int n = t; n < NLQ; n += 256) {
    const float* hr = h + ((size_t)b * NQ + n) * DQ;
    float s = 0.f;
#pragma unroll
    for (int d = 0; d < 128; d += 4) {
      float4 hv = *(const float4*)(hr + d);
      s += hv.x * lw[d] + hv.y * lw[d + 1] + hv.z * lw[d + 2] + hv.w * lw[d + 3];
    }
    lg[n] = (node[b * NLQ + n] == 2) ? (s + bias) : -1e9f;
  }
  __syncthreads();
  int lane = t & 63, w = t >> 6;
  float mx = -3.0e38f;
  for (int n = t; n < NLQ; n += 256) mx = fmaxf(mx, lg[n]);
  mx = waveMax(mx);
  if (lane == 0) red[w] = mx;
  __syncthreads();
  if (t == 0) bc = fmaxf(fmaxf(red[0], red[1]), fmaxf(red[2], red[3]));
  __syncthreads();
  float M = bc;
  float sum = 0.f;
  for (int n = t; n < NLQ; n += 256) {
    float e = expf(lg[n] - M);
    lg[n] = e;
    sum += e;
  }
  __syncthreads();
  sum = waveSum(sum);
  if (lane == 0) red[w] = sum;
  __syncthreads();
  if (t == 0) bc = red[0] + red[1] + red[2] + red[3];
  __syncthreads();
  float inv = 1.f / bc;
  float loss = 0.f;
  for (int n = t; n < NLQ; n += 256) {
    float sm = lg[n] * inv;
    outSm[b * NLQ + n] = sm;
    float c = fminf(fmaxf(sm, 1e-10f), 1.f);
    loss += -logf(c) * res[b * NLQ + n];
  }
  loss = waveSum(loss);
  __syncthreads();
  if (lane == 0) red[w] = loss;
  __syncthreads();
  if (t == 0) outLoss[b] = red[0] + red[1] + red[2] + red[3];
}

__global__ void copy_x(const float4* __restrict__ h, float4* __restrict__ out) {
  int idx = blockIdx.x * 256 + threadIdx.x;  // 8*1024*32 = 262144 exactly
  int r = idx >> 5;
  int c = idx & 31;
  int b = r >> 10, n = r & 1023;
  out[idx] = h[((size_t)b * NQ + n) * 32 + c];
}

__global__ void ws_fail(float* out) {
  if (threadIdx.x == 0) out[0] = -7.0e7f;  // sentinel: workspace too small
}

// ---------------------------------------------------------------------------
extern "C" void kernel_launch(void* const* d_in, const int* in_sizes, int n_in,
                              void* d_out, int out_size, void* d_ws, size_t ws_size,
                              hipStream_t stream) {
  const int* input_node = (const int*)d_in[0];
  const float* inputad  = (const float*)d_in[2];
  const float* res      = (const float*)d_in[3];
  const int* inputtext  = (const int*)d_in[4];
  const int* linenode   = (const int*)d_in[5];
  const float* tok_emb  = (const float*)d_in[8];
  const float* tok_emb1 = (const float*)d_in[9];
  const float* in_W  = (const float*)d_in[10];
  const float* in_b  = (const float*)d_in[11];
  const float* ug_W  = (const float*)d_in[12];
  const float* ug_b  = (const float*)d_in[13];
  const float* rg_W  = (const float*)d_in[14];
  const float* rg_b  = (const float*)d_in[15];
  const float* ht_W  = (const float*)d_in[16];
  const float* ht_b  = (const float*)d_in[17];
  const float* res2_W = (const float*)d_in[18];
  const float* res2_b = (const float*)d_in[19];

  char* ws = (char*)d_ws;
  const size_t OFF_ADJ = 0;
  const size_t OFF_H   = OFF_ADJ + (size_t)BQ * NQ * NQ * 2;       // adj bf16, 67 MB
  const size_t OFF_Z   = OFF_H   + (size_t)BQ * NQ * DQ * 4;       // h fp32
  const size_t OFF_HBF = OFF_Z   + (size_t)BQ * NQ * DQ * 4;       // z fp32
  const size_t OFF_HT  = OFF_HBF + (size_t)BQ * NQ * DQ * 2;       // h bf16 row-major
  const size_t OFF_MS  = OFF_HT  + (size_t)BQ * NQ * DQ * 2;       // hT bf16 [b][d][n]
  const size_t OFF_RH  = OFF_MS  + (size_t)2 * BQ * NQ * DQ * 2;   // msgs partials x2
  const size_t OFF_WZR = OFF_RH  + (size_t)BQ * NQ * DQ * 2;       // r*h bf16
  const size_t OFF_HTW = OFF_WZR + (size_t)5 * 256 * 256 * 2;
  const size_t OFF_INW = OFF_HTW + (size_t)5 * 128 * 256 * 2;
  const size_t NEED    = OFF_INW + (size_t)5 * 128 * 128 * 2;      // ~101 MB
  if (ws_size < NEED) {
    ws_fail<<<1, 64, 0, stream>>>((float*)d_out);
    return;
  }

  __hip_bfloat16* adjbf = (__hip_bfloat16*)(ws + OFF_ADJ);
  float* hF             = (float*)(ws + OFF_H);
  float* zF             = (float*)(ws + OFF_Z);
  __hip_bfloat16* hbf   = (__hip_bfloat16*)(ws + OFF_HBF);
  __hip_bfloat16* hT    = (__hip_bfloat16*)(ws + OFF_HT);
  __hip_bfloat16* msbf  = (__hip_bfloat16*)(ws + OFF_MS);
  __hip_bfloat16* rhbf  = (__hip_bfloat16*)(ws + OFF_RH);
  __hip_bfloat16* wzrT  = (__hip_bfloat16*)(ws + OFF_WZR);
  __hip_bfloat16* htT   = (__hip_bfloat16*)(ws + OFF_HTW);
  __hip_bfloat16* inT   = (__hip_bfloat16*)(ws + OFF_INW);

  float* outLoss = (float*)d_out;
  float* outSm = outLoss + BQ;
  float* outX = outSm + BQ * NLQ;

  cvt_adj<<<4096, 256, 0, stream>>>((const float4*)inputad, (ushort4*)adjbf,
                                    (int)((size_t)BQ * NQ * NQ / 4));
  pack_weights<<<2240, 256, 0, stream>>>(ug_W, rg_W, ht_W, in_W, wzrT, htT, inT);
  build_x<<<8192, 256, 0, stream>>>(input_node, inputtext, linenode, tok_emb, tok_emb1, hbf);

  for (int i = 0; i < 5; ++i) {
    // h = x @ in_W[i] + in_b[i]  (in-place: each block reads only its own rows)
    gemm_small<3><<<dim3(128, 1), 256, 0, stream>>>(
        hbf, nullptr, inT + i * 128 * 128, 128,
        in_b + i * 128, nullptr, hF, nullptr, hbf, hT);
    for (int s = 0; s < 3; ++s) {
      // msgs partials = adj @ h (split-K halves)
      gemm_msgs<<<dim3(16, 1, 16), 256, 0, stream>>>(adjbf, hT, msbf);
      // z = sigmoid([h|ms]@ug), rh = sigmoid([h|ms]@rg) * h
      gemm_small<1><<<dim3(128, 2), 256, 0, stream>>>(
          hbf, msbf, wzrT + i * 256 * 256, 256,
          ug_b + i * 128, rg_b + i * 128, hF, zF, rhbf, nullptr);
      // h = z*h + (1-z)*tanh([rh|ms]@ht)
      gemm_small<2><<<dim3(128, 1), 256, 0, stream>>>(
          rhbf, msbf, htT + i * 128 * 256, 256,
          ht_b + i * 128, nullptr, hF, zF, hbf, hT);
    }
  }

  final_k<<<8, 256, 0, stream>>>(hF, res2_W, res2_b, input_node, res, outLoss, outSm);
  copy_x<<<1024, 256, 0, stream>>>((const float4*)hF, (float4*)outX);
}

// Round 4
// 750.713 us; speedup vs baseline: 1.5940x; 1.5940x over previous
//
#include <hip/hip_runtime.h>
#include <hip/hip_bf16.h>

// Problem constants
#define BQ   8
#define NLQ  1024
#define NQ   2048
#define DQ   128

typedef __attribute__((ext_vector_type(4))) float f32x4;
typedef __attribute__((ext_vector_type(8))) short bf16x8;

__device__ __forceinline__ unsigned short bfbits(float f) {
  __hip_bfloat16 h = __float2bfloat16(f);
  return __builtin_bit_cast(unsigned short, h);
}
__device__ __forceinline__ float sigm(float x) { return 1.f / (1.f + expf(-x)); }

// packed bf16 pair add (truncating round — threshold slack is huge)
__device__ __forceinline__ unsigned int bfadd2(unsigned int a, unsigned int b) {
  float alo = __builtin_bit_cast(float, a << 16);
  float ahi = __builtin_bit_cast(float, a & 0xffff0000u);
  float blo = __builtin_bit_cast(float, b << 16);
  float bhi = __builtin_bit_cast(float, b & 0xffff0000u);
  float lo = alo + blo, hi = ahi + bhi;
  return (__builtin_bit_cast(unsigned int, hi) & 0xffff0000u) |
         (__builtin_bit_cast(unsigned int, lo) >> 16);
}

// async global->LDS, 16B per lane. LDS dest is wave-uniform base + lane*16.
__device__ __forceinline__ void g2l16(const void* g, void* l) {
  __builtin_amdgcn_global_load_lds(
      (__attribute__((address_space(1))) void*)(uintptr_t)g,
      (__attribute__((address_space(3))) void*)(uint32_t)(uintptr_t)l,
      16, 0, 0);
}

// ---------------------------------------------------------------------------
// msgs GEMM, split-K-2: msP[kh][b] = adj[b][:, kh*1024+*] @ h[kh*1024+*][:]
// Tile 64(M) x 128(N), BK=64, 4 waves (2x2), wave tile 32x64. 72 KB LDS ->
// 2 blocks/CU. Grid (32,1,16) = 512 blocks = machine-filling.
// 3-buffer LDS, 2-deep prefetch, counted vmcnt(6).
// ---------------------------------------------------------------------------
__global__ __launch_bounds__(256) void gemm_msgs(
    const __hip_bfloat16* __restrict__ adj,   // [B][2048][2048]
    const __hip_bfloat16* __restrict__ hT,    // [B][128][2048]
    __hip_bfloat16* __restrict__ msP) {       // [2][B][2048][128]
  __shared__ __align__(16) __hip_bfloat16 As[3][64 * 64];
  __shared__ __align__(16) __hip_bfloat16 Bs[3][128 * 64];
  const int t = threadIdx.x, lane = t & 63, w = t >> 6;
  const int wr = w >> 1, wc = w & 1;
  const int bm = blockIdx.x;
  const int batch = blockIdx.z >> 1, kh = blockIdx.z & 1;

  const __hip_bfloat16* aB = adj + (size_t)batch * NQ * NQ + (size_t)bm * 64 * NQ + kh * 1024;
  const __hip_bfloat16* bB = hT + (size_t)batch * DQ * NQ + kh * 1024;

  const int srA = w * 16 + (lane >> 3);
  const int srB = w * 32 + (lane >> 3);
  const int swzCol = ((lane & 7) ^ (lane >> 3)) << 3;
  const int lr = lane & 15, lh = lane >> 4;
  const int rswz = (lr & 7) << 3;

  f32x4 acc[2][4] = {};

  auto stage = [&](int bi, int tt) {
    const int k = tt * 64;
#pragma unroll
    for (int q = 0; q < 2; ++q)
      g2l16(aB + (size_t)(srA + q * 8) * NQ + k + swzCol,
            (char*)As[bi] + w * 2048 + q * 1024);
#pragma unroll
    for (int q = 0; q < 4; ++q)
      g2l16(bB + (size_t)(srB + q * 8) * NQ + k + swzCol,
            (char*)Bs[bi] + w * 4096 + q * 1024);
  };

  stage(0, 0);
  stage(1, 1);
  asm volatile("s_waitcnt vmcnt(6)" ::: "memory");
  __builtin_amdgcn_s_barrier();

  int cur = 0;
  const int nt = 16;  // 1024/64
  for (int tt = 0; tt < nt; ++tt) {
    bf16x8 av[2][2], bv[2][4];
#pragma unroll
    for (int kk = 0; kk < 2; ++kk) {
#pragma unroll
      for (int m = 0; m < 2; ++m)
        av[kk][m] = *(const bf16x8*)&As[cur][(wr * 32 + m * 16 + lr) * 64 +
                                            ((kk * 32 + lh * 8) ^ rswz)];
#pragma unroll
      for (int n = 0; n < 4; ++n)
        bv[kk][n] = *(const bf16x8*)&Bs[cur][(wc * 64 + n * 16 + lr) * 64 +
                                             ((kk * 32 + lh * 8) ^ rswz)];
    }
    if (tt + 2 < nt) {
      int bi = cur + 2; if (bi >= 3) bi -= 3;
      stage(bi, tt + 2);
    }
    __builtin_amdgcn_s_setprio(1);
#pragma unroll
    for (int kk = 0; kk < 2; ++kk)
#pragma unroll
      for (int m = 0; m < 2; ++m)
#pragma unroll
        for (int n = 0; n < 4; ++n)
          acc[m][n] = __builtin_amdgcn_mfma_f32_16x16x32_bf16(av[kk][m], bv[kk][n],
                                                              acc[m][n], 0, 0, 0);
    __builtin_amdgcn_s_setprio(0);
    if (tt < nt - 2) {
      asm volatile("s_waitcnt vmcnt(6)" ::: "memory");
      __builtin_amdgcn_s_barrier();
    } else if (tt == nt - 2) {
      asm volatile("s_waitcnt vmcnt(0)" ::: "memory");
      __builtin_amdgcn_s_barrier();
    }
    ++cur; if (cur == 3) cur = 0;
  }

  __hip_bfloat16* out = msP + (size_t)kh * (BQ * NQ * DQ) + (size_t)batch * NQ * DQ;
#pragma unroll
  for (int m = 0; m < 2; ++m) {
    const int row0 = bm * 64 + wr * 32 + m * 16 + lh * 4;
#pragma unroll
    for (int n = 0; n < 4; ++n) {
      const int col = wc * 64 + n * 16 + lr;
#pragma unroll
      for (int r = 0; r < 4; ++r)
        out[(size_t)(row0 + r) * DQ + col] = __float2bfloat16(acc[m][n][r]);
    }
  }
}

// ---------------------------------------------------------------------------
// Token GEMMs (M=16384): C = [A0 | ms0+ms1] @ BT^T.  Tile 64x128, BK=64,
// 4 waves, 3-buffer pipeline, counted vmcnt. A-cols >= 128 are the summed
// msgs partials, staged global->reg->bfadd->ds_write (issued before B's
// g2l16 so the use-wait is vmcnt(4), not a drain).
// EPI: 1 = z/r+rh, 2 = ht+GRU update, 3 = in-proj.
// ---------------------------------------------------------------------------
template <int EPI>
__global__ __launch_bounds__(256) void gemm_small(
    const __hip_bfloat16* __restrict__ A0,   // [16384][128]
    const __hip_bfloat16* __restrict__ ms,   // [2][16384][128] partials or null
    const __hip_bfloat16* __restrict__ BT,   // [Ncols][K]
    int K,
    const float* __restrict__ bias0, const float* __restrict__ bias1,
    float* __restrict__ hF, float* __restrict__ zF,
    __hip_bfloat16* __restrict__ bf0, __hip_bfloat16* __restrict__ bf1) {
  __shared__ __align__(16) __hip_bfloat16 As[3][64 * 64];
  __shared__ __align__(16) __hip_bfloat16 Bs[3][128 * 64];
  const int t = threadIdx.x, lane = t & 63, w = t >> 6;
  const int wr = w >> 1, wc = w & 1;
  const int bm = blockIdx.x, bn = blockIdx.y;

  const int swzCol = ((lane & 7) ^ (lane >> 3)) << 3;
  const int lr = lane & 15, lh = lane >> 4;
  const int rswz = (lr & 7) << 3;
  const size_t msStride = (size_t)BQ * NQ * DQ;

  const int nt = K >> 6;
  f32x4 acc[2][4] = {};
  uint4 p0[2], p1[2];

  auto stageB = [&](int bi, int tt) {
#pragma unroll
    for (int q = 0; q < 4; ++q)
      g2l16(BT + (size_t)(bn * 128 + w * 32 + q * 8 + (lane >> 3)) * K + tt * 64 + swzCol,
            (char*)Bs[bi] + w * 4096 + q * 1024);
  };
  // returns true if reg path (partial-sum) was used; reg loads issued FIRST
  auto stageA = [&](int bi, int tt) -> bool {
    const int k0 = tt * 64;
    if (k0 < 128 || ms == nullptr) {
#pragma unroll
      for (int q = 0; q < 2; ++q)
        g2l16(A0 + (size_t)(bm * 64 + w * 16 + q * 8 + (lane >> 3)) * 128 + k0 + swzCol,
              (char*)As[bi] + w * 2048 + q * 1024);
      return false;
    }
    const size_t base = (size_t)(bm * 64 + w * 16 + (lane >> 3)) * 128 + (k0 - 128) + swzCol;
#pragma unroll
    for (int q = 0; q < 2; ++q) {
      p0[q] = *(const uint4*)(ms + base + (size_t)q * 8 * 128);
      p1[q] = *(const uint4*)(ms + msStride + base + (size_t)q * 8 * 128);
    }
    return true;
  };
  auto finalize = [&](int bi) {
#pragma unroll
    for (int q = 0; q < 2; ++q) {
      uint4 s;
      s.x = bfadd2(p0[q].x, p1[q].x);
      s.y = bfadd2(p0[q].y, p1[q].y);
      s.z = bfadd2(p0[q].z, p1[q].z);
      s.w = bfadd2(p0[q].w, p1[q].w);
      *(uint4*)((char*)As[bi] + w * 2048 + q * 1024 + lane * 16) = s;
    }
  };

  stageA(0, 0);  // k0=0 -> always direct
  stageB(0, 0);
  stageA(1, 1);  // k0=64 -> always direct
  stageB(1, 1);
  asm volatile("s_waitcnt vmcnt(6)" ::: "memory");
  __builtin_amdgcn_s_barrier();

  int cur = 0;
  for (int tt = 0; tt < nt; ++tt) {
    bf16x8 av[2][2], bv[2][4];
#pragma unroll
    for (int kk = 0; kk < 2; ++kk) {
#pragma unroll
      for (int m = 0; m < 2; ++m)
        av[kk][m] = *(const bf16x8*)&As[cur][(wr * 32 + m * 16 + lr) * 64 +
                                            ((kk * 32 + lh * 8) ^ rswz)];
#pragma unroll
      for (int n = 0; n < 4; ++n)
        bv[kk][n] = *(const bf16x8*)&Bs[cur][(wc * 64 + n * 16 + lr) * 64 +
                                             ((kk * 32 + lh * 8) ^ rswz)];
    }
    bool reg = false;
    int bi = cur + 2; if (bi >= 3) bi -= 3;
    if (tt + 2 < nt) {
      reg = stageA(bi, tt + 2);
      stageB(bi, tt + 2);
    }
    __builtin_amdgcn_s_setprio(1);
#pragma unroll
    for (int kk = 0; kk < 2; ++kk)
#pragma unroll
      for (int m = 0; m < 2; ++m)
#pragma unroll
        for (int n = 0; n < 4; ++n)
          acc[m][n] = __builtin_amdgcn_mfma_f32_16x16x32_bf16(av[kk][m], bv[kk][n],
                                                              acc[m][n], 0, 0, 0);
    __builtin_amdgcn_s_setprio(0);
    if (reg) finalize(bi);
    if (tt < nt - 2) {
      if (reg)
        asm volatile("s_waitcnt vmcnt(4) lgkmcnt(0)" ::: "memory");
      else
        asm volatile("s_waitcnt vmcnt(6) lgkmcnt(0)" ::: "memory");
      __builtin_amdgcn_s_barrier();
    } else if (tt == nt - 2) {
      asm volatile("s_waitcnt vmcnt(0) lgkmcnt(0)" ::: "memory");
      __builtin_amdgcn_s_barrier();
    }
    ++cur; if (cur == 3) cur = 0;
  }

  // Epilogue. C/D layout: col = lane&15, row = (lane>>4)*4 + reg.
#pragma unroll
  for (int m = 0; m < 2; ++m) {
    const int gRow = bm * 64 + wr * 32 + m * 16 + lh * 4;
#pragma unroll
    for (int n = 0; n < 4; ++n) {
      const int col = bn * 128 + wc * 64 + n * 16 + lr;
      f32x4 v = acc[m][n];
      if constexpr (EPI == 1) {  // z (bn==0) / r -> r*h (bn==1)
        if (col < 128) {
          const float bb = bias0[col];
#pragma unroll
          for (int r = 0; r < 4; ++r)
            zF[(size_t)(gRow + r) * DQ + col] = sigm(v[r] + bb);
        } else {
          const int c = col - 128;
          const float bb = bias1[c];
#pragma unroll
          for (int r = 0; r < 4; ++r) {
            size_t idx = (size_t)(gRow + r) * DQ + c;
            float rr = sigm(v[r] + bb);
            bf0[idx] = __float2bfloat16(rr * hF[idx]);
          }
        }
      } else {  // EPI 2 (ht + GRU) and EPI 3 (in-proj)
        const float bb = bias0[col];
        ushort4 us;
        unsigned short* up = (unsigned short*)&us;
#pragma unroll
        for (int r = 0; r < 4; ++r) {
          size_t idx = (size_t)(gRow + r) * DQ + col;
          float hn;
          if constexpr (EPI == 2) {
            float tv = tanhf(v[r] + bb);
            float zv = zF[idx];
            float hv = hF[idx];
            hn = zv * hv + (1.f - zv) * tv;
          } else {
            hn = v[r] + bb;
          }
          hF[idx] = hn;
          bf0[idx] = __float2bfloat16(hn);
          up[r] = bfbits(hn);
        }
        const int bb_ = gRow >> 11;
        const int nl = gRow & 2047;
        *(ushort4*)((char*)bf1 + ((size_t)bb_ * (DQ * NQ) + (size_t)col * NQ + nl) * 2) = us;
      }
    }
  }
}

// ---------------------------------------------------------------------------
__global__ void cvt_adj(const float4* __restrict__ in, ushort4* __restrict__ out, int n4) {
  int stride = gridDim.x * blockDim.x;
  for (int i = blockIdx.x * blockDim.x + threadIdx.x; i < n4; i += stride) {
    float4 v = in[i];
    ushort4 o;
    o.x = bfbits(v.x); o.y = bfbits(v.y); o.z = bfbits(v.z); o.w = bfbits(v.w);
    out[i] = o;
  }
}

// Pack weights to bf16, transposed to N x K row-major.
__global__ void pack_weights(const float* __restrict__ ugW, const float* __restrict__ rgW,
                             const float* __restrict__ htW, const float* __restrict__ inW,
                             __hip_bfloat16* __restrict__ wzrT, __hip_bfloat16* __restrict__ htT,
                             __hip_bfloat16* __restrict__ inT) {
  int idx = blockIdx.x * 256 + threadIdx.x;
  if (idx < 5 * 256 * 256) {  // wzrT[i][n][k], n<128 -> ug, else rg
    int i = idx >> 16, r = idx & 65535, nn = r >> 8, k = r & 255;
    float v = (nn < 128) ? ugW[(i * 256 + k) * 128 + nn] : rgW[(i * 256 + k) * 128 + nn - 128];
    wzrT[idx] = __float2bfloat16(v);
    return;
  }
  int j = idx - 5 * 256 * 256;
  if (j < 5 * 128 * 256) {  // htT[i][n][k]
    int i = j >> 15, r = j & 32767, nn = r >> 8, k = r & 255;
    htT[j] = __float2bfloat16(htW[(i * 256 + k) * 128 + nn]);
    return;
  }
  int j2 = j - 5 * 128 * 256;
  if (j2 < 5 * 128 * 128) {  // inT[i][n][k]
    int i = j2 >> 14, r = j2 & 16383, nn = r >> 7, k = r & 127;
    inT[j2] = __float2bfloat16(inW[(i * 128 + k) * 128 + nn]);
  }
}

// Build initial x (bf16) = [tok_emb[input_node] | inputtext] ++ tok_emb1[linenode]
__global__ void build_x(const int* __restrict__ node, const int* __restrict__ text,
                        const int* __restrict__ line, const float* __restrict__ te,
                        const float* __restrict__ te1, __hip_bfloat16* __restrict__ xbf) {
  int idx = blockIdx.x * 256 + threadIdx.x;  // B*N*D = 2M exactly
  int d = idx & 127;
  int p = (idx >> 7) & 2047;
  int b = idx >> 18;
  float v;
  if (p < NLQ) {
    if (d < 127) {
      int id = node[b * NLQ + p];
      v = te[(size_t)id * 127 + d];
    } else {
      v = (float)text[b * NLQ + p];
    }
  } else {
    int id = line[b * NLQ + (p - NLQ)];
    v = te1[(size_t)id * 128 + d];
  }
  xbf[idx] = __float2bfloat16(v);
}

__device__ __forceinline__ float waveMax(float v) {
#pragma unroll
  for (int m = 32; m; m >>= 1) v = fmaxf(v, __shfl_xor(v, m, 64));
  return v;
}
__device__ __forceinline__ float waveSum(float v) {
#pragma unroll
  for (int m = 32; m; m >>= 1) v += __shfl_xor(v, m, 64);
  return v;
}

// logits = h[:, :NL] @ res2_W + b; mask; softmax; loss. 1024 thr, 1 row/thr.
__global__ __launch_bounds__(1024) void final_k(const float* __restrict__ h,
                                                const float* __restrict__ w2,
                                                const float* __restrict__ b2,
                                                const int* __restrict__ node,
                                                const float* __restrict__ res,
                                                float* __restrict__ outLoss,
                                                float* __restrict__ outSm) {
  int b = blockIdx.x, t = threadIdx.x;
  __shared__ float lw[128];
  __shared__ float red[16];
  __shared__ float bc;
  if (t < 128) lw[t] = w2[t];
  __syncthreads();
  const float* hr = h + ((size_t)b * NQ + t) * DQ;
  float s = 0.f;
#pragma unroll
  for (int d = 0; d < 128; d += 4) {
    float4 hv = *(const float4*)(hr + d);
    s += hv.x * lw[d] + hv.y * lw[d + 1] + hv.z * lw[d + 2] + hv.w * lw[d + 3];
  }
  float lg = (node[b * NLQ + t] == 2) ? (s + b2[0]) : -1e9f;
  int lane = t & 63, w = t >> 6;
  float mx = waveMax(lg);
  if (lane == 0) red[w] = mx;
  __syncthreads();
  if (t == 0) {
    float m = red[0];
#pragma unroll
    for (int i = 1; i < 16; ++i) m = fmaxf(m, red[i]);
    bc = m;
  }
  __syncthreads();
  float M = bc;
  float e = expf(lg - M);
  float sum = waveSum(e);
  __syncthreads();  // all reads of bc done before overwrite
  if (lane == 0) red[w] = sum;
  __syncthreads();
  if (t == 0) {
    float tot = 0.f;
#pragma unroll
    for (int i = 0; i < 16; ++i) tot += red[i];
    bc = tot;
  }
  __syncthreads();
  float sm = e / bc;
  outSm[b * NLQ + t] = sm;
  float c = fminf(fmaxf(sm, 1e-10f), 1.f);
  float loss = waveSum(-logf(c) * res[b * NLQ + t]);
  __syncthreads();
  if (lane == 0) red[w] = loss;
  __syncthreads();
  if (t == 0) {
    float tot = 0.f;
#pragma unroll
    for (int i = 0; i < 16; ++i) tot += red[i];
    outLoss[b] = tot;
  }
}

__global__ void copy_x(const float4* __restrict__ h, float4* __restrict__ out) {
  int idx = blockIdx.x * 256 + threadIdx.x;  // 8*1024*32 = 262144 exactly
  int r = idx >> 5;
  int c = idx & 31;
  int b = r >> 10, n = r & 1023;
  out[idx] = h[((size_t)b * NQ + n) * 32 + c];
}

__global__ void ws_fail(float* out) {
  if (threadIdx.x == 0) out[0] = -7.0e7f;  // sentinel: workspace too small
}

// ---------------------------------------------------------------------------
extern "C" void kernel_launch(void* const* d_in, const int* in_sizes, int n_in,
                              void* d_out, int out_size, void* d_ws, size_t ws_size,
                              hipStream_t stream) {
  const int* input_node = (const int*)d_in[0];
  const float* inputad  = (const float*)d_in[2];
  const float* res      = (const float*)d_in[3];
  const int* inputtext  = (const int*)d_in[4];
  const int* linenode   = (const int*)d_in[5];
  const float* tok_emb  = (const float*)d_in[8];
  const float* tok_emb1 = (const float*)d_in[9];
  const float* in_W  = (const float*)d_in[10];
  const float* in_b  = (const float*)d_in[11];
  const float* ug_W  = (const float*)d_in[12];
  const float* ug_b  = (const float*)d_in[13];
  const float* rg_W  = (const float*)d_in[14];
  const float* rg_b  = (const float*)d_in[15];
  const float* ht_W  = (const float*)d_in[16];
  const float* ht_b  = (const float*)d_in[17];
  const float* res2_W = (const float*)d_in[18];
  const float* res2_b = (const float*)d_in[19];

  char* ws = (char*)d_ws;
  const size_t OFF_ADJ = 0;
  const size_t OFF_H   = OFF_ADJ + (size_t)BQ * NQ * NQ * 2;       // adj bf16, 67 MB
  const size_t OFF_Z   = OFF_H   + (size_t)BQ * NQ * DQ * 4;       // h fp32
  const size_t OFF_HBF = OFF_Z   + (size_t)BQ * NQ * DQ * 4;       // z fp32
  const size_t OFF_HT  = OFF_HBF + (size_t)BQ * NQ * DQ * 2;       // h bf16 row-major
  const size_t OFF_MS  = OFF_HT  + (size_t)BQ * NQ * DQ * 2;       // hT bf16 [b][d][n]
  const size_t OFF_RH  = OFF_MS  + (size_t)2 * BQ * NQ * DQ * 2;   // msgs partials x2
  const size_t OFF_WZR = OFF_RH  + (size_t)BQ * NQ * DQ * 2;       // r*h bf16
  const size_t OFF_HTW = OFF_WZR + (size_t)5 * 256 * 256 * 2;
  const size_t OFF_INW = OFF_HTW + (size_t)5 * 128 * 256 * 2;
  const size_t NEED    = OFF_INW + (size_t)5 * 128 * 128 * 2;      // ~101 MB
  if (ws_size < NEED) {
    ws_fail<<<1, 64, 0, stream>>>((float*)d_out);
    return;
  }

  __hip_bfloat16* adjbf = (__hip_bfloat16*)(ws + OFF_ADJ);
  float* hF             = (float*)(ws + OFF_H);
  float* zF             = (float*)(ws + OFF_Z);
  __hip_bfloat16* hbf   = (__hip_bfloat16*)(ws + OFF_HBF);
  __hip_bfloat16* hT    = (__hip_bfloat16*)(ws + OFF_HT);
  __hip_bfloat16* msbf  = (__hip_bfloat16*)(ws + OFF_MS);
  __hip_bfloat16* rhbf  = (__hip_bfloat16*)(ws + OFF_RH);
  __hip_bfloat16* wzrT  = (__hip_bfloat16*)(ws + OFF_WZR);
  __hip_bfloat16* htT   = (__hip_bfloat16*)(ws + OFF_HTW);
  __hip_bfloat16* inT   = (__hip_bfloat16*)(ws + OFF_INW);

  float* outLoss = (float*)d_out;
  float* outSm = outLoss + BQ;
  float* outX = outSm + BQ * NLQ;

  cvt_adj<<<4096, 256, 0, stream>>>((const float4*)inputad, (ushort4*)adjbf,
                                    (int)((size_t)BQ * NQ * NQ / 4));
  pack_weights<<<2240, 256, 0, stream>>>(ug_W, rg_W, ht_W, in_W, wzrT, htT, inT);
  build_x<<<8192, 256, 0, stream>>>(input_node, inputtext, linenode, tok_emb, tok_emb1, hbf);

  for (int i = 0; i < 5; ++i) {
    // h = x @ in_W[i] + in_b[i]  (in-place: each block reads only its own rows)
    gemm_small<3><<<dim3(256, 1), 256, 0, stream>>>(
        hbf, nullptr, inT + i * 128 * 128, 128,
        in_b + i * 128, nullptr, hF, nullptr, hbf, hT);
    for (int s = 0; s < 3; ++s) {
      // msgs partials = adj @ h (split-K halves)
      gemm_msgs<<<dim3(32, 1, 16), 256, 0, stream>>>(adjbf, hT, msbf);
      // z = sigmoid([h|ms]@ug), rh = sigmoid([h|ms]@rg) * h
      gemm_small<1><<<dim3(256, 2), 256, 0, stream>>>(
          hbf, msbf, wzrT + i * 256 * 256, 256,
          ug_b + i * 128, rg_b + i * 128, hF, zF, rhbf, nullptr);
      // h = z*h + (1-z)*tanh([rh|ms]@ht)
      gemm_small<2><<<dim3(256, 1), 256, 0, stream>>>(
          rhbf, msbf, htT + i * 128 * 256, 256,
          ht_b + i * 128, nullptr, hF, zF, hbf, hT);
    }
  }

  final_k<<<8, 1024, 0, stream>>>(hF, res2_W, res2_b, input_node, res, outLoss, outSm);
  copy_x<<<1024, 256, 0, stream>>>((const float4*)hF, (float4*)outX);
}